// Round 1
// baseline (3874.539 us; speedup 1.0000x reference)
//
#include <hip/hip_runtime.h>

// GCN encoder: h = x@W.T; symmetric-norm aggregate with self-loops; +b; PReLU.
// N=50000, F=128, H=512, E=400000 (derived from in_sizes at runtime).

#define F_IN 128
#define H_OUT 512

__global__ __launch_bounds__(256) void zero_deg_kernel(unsigned* __restrict__ deg, int n) {
    int i = blockIdx.x * 256 + threadIdx.x;
    if (i < n) deg[i] = 0u;
}

__global__ __launch_bounds__(256) void count_deg_kernel(const int* __restrict__ col,
                                                        unsigned* __restrict__ deg, int E) {
    int e = blockIdx.x * 256 + threadIdx.x;
    if (e < E) atomicAdd(&deg[col[e]], 1u);
}

__global__ __launch_bounds__(256) void dinv_kernel(const unsigned* __restrict__ deg,
                                                   float* __restrict__ dinv, int n) {
    int i = blockIdx.x * 256 + threadIdx.x;
    if (i < n) dinv[i] = rsqrtf((float)(deg[i] + 1u));  // +1 for self-loop
}

// Tiled fp32 GEMM: h[n,c] = sum_k x[n,k]*W[c,k]; epilogue scales by dinv[n],
// writes hs (workspace) and initializes out = hs (self-loop contribution).
// Tile: 64 rows x 32 cols, 256 threads = 16(ty) x 16(tx), 4x2 outputs/thread.
__global__ __launch_bounds__(256) void gemm_kernel(const float* __restrict__ x,
                                                   const float* __restrict__ W,
                                                   const float* __restrict__ dinv,
                                                   float* __restrict__ hs,
                                                   float* __restrict__ out, int N) {
    __shared__ float xs[64][132];  // pad 4: row stride 528B, 2-way max conflict
    __shared__ float ws[32][136];  // pad 8: per-tx stride 272 floats -> 2-way

    const int rb = blockIdx.x * 64;
    const int cb = blockIdx.y * 32;
    const int t  = threadIdx.x;

    // Load x tile: rows rb..rb+63 are a contiguous 8192-float region (full rows).
    #pragma unroll
    for (int i = 0; i < 8; ++i) {
        int lin = i * 256 + t;          // float4 index, 0..2047
        int r   = lin >> 5;             // 32 float4 per row
        int k4  = lin & 31;
        float4 v = make_float4(0.f, 0.f, 0.f, 0.f);
        if (rb + r < N) v = *(const float4*)(x + (size_t)(rb + r) * F_IN + k4 * 4);
        *(float4*)(&xs[r][k4 * 4]) = v;
    }
    // Load W tile: 32 rows x 128 = 1024 float4 (H=512 multiple of 32, always in range).
    #pragma unroll
    for (int i = 0; i < 4; ++i) {
        int lin = i * 256 + t;
        int r   = lin >> 5;
        int k4  = lin & 31;
        float4 v = *(const float4*)(W + (size_t)(cb + r) * F_IN + k4 * 4);
        *(float4*)(&ws[r][k4 * 4]) = v;
    }
    __syncthreads();

    const int ty = t >> 4;   // 0..15 -> rows ty*4..ty*4+3
    const int tx = t & 15;   // 0..15 -> cols tx*2..tx*2+1

    float acc[4][2] = {};
    #pragma unroll
    for (int k = 0; k < F_IN; k += 4) {
        float4 xv[4], wv[2];
        #pragma unroll
        for (int i = 0; i < 4; ++i) xv[i] = *(const float4*)(&xs[ty * 4 + i][k]);
        #pragma unroll
        for (int j = 0; j < 2; ++j) wv[j] = *(const float4*)(&ws[tx * 2 + j][k]);
        #pragma unroll
        for (int i = 0; i < 4; ++i)
            #pragma unroll
            for (int j = 0; j < 2; ++j)
                acc[i][j] += xv[i].x * wv[j].x + xv[i].y * wv[j].y +
                             xv[i].z * wv[j].z + xv[i].w * wv[j].w;
    }

    #pragma unroll
    for (int i = 0; i < 4; ++i) {
        int r = rb + ty * 4 + i;
        if (r >= N) continue;
        float dv = dinv[r];
        #pragma unroll
        for (int j = 0; j < 2; ++j) {
            int c = cb + tx * 2 + j;
            float v = acc[i][j] * dv;
            hs[(size_t)r * H_OUT + c]  = v;   // gather source for scatter
            out[(size_t)r * H_OUT + c] = v;   // self-loop init of accumulator
        }
    }
}

// One wave per edge: out[col[e]] += hs[row[e]]  (512 floats, 8 atomics/lane).
__global__ __launch_bounds__(256) void scatter_kernel(const int* __restrict__ row,
                                                      const int* __restrict__ col,
                                                      const float* __restrict__ hs,
                                                      float* __restrict__ out, int E) {
    int wid  = (int)((blockIdx.x * 256 + threadIdx.x) >> 6);
    int lane = threadIdx.x & 63;
    if (wid >= E) return;
    int r = row[wid];
    int c = col[wid];
    const float4* src = (const float4*)(hs + (size_t)r * H_OUT);
    float*        dst = out + (size_t)c * H_OUT;
    #pragma unroll
    for (int j = 0; j < 2; ++j) {
        int f4 = j * 64 + lane;          // 0..127 float4 slots
        float4 v = src[f4];
        int base = f4 * 4;
        unsafeAtomicAdd(dst + base + 0, v.x);
        unsafeAtomicAdd(dst + base + 1, v.y);
        unsafeAtomicAdd(dst + base + 2, v.z);
        unsafeAtomicAdd(dst + base + 3, v.w);
    }
}

// out = prelu(dinv[n] * acc + b, alpha), vectorized float4 over N*128 slots.
__global__ __launch_bounds__(256) void finalize_kernel(float* __restrict__ out,
                                                       const float* __restrict__ dinv,
                                                       const float* __restrict__ b,
                                                       const float* __restrict__ alpha,
                                                       int N) {
    int idx = blockIdx.x * 256 + threadIdx.x;     // float4 index
    int total = N * (H_OUT / 4);
    if (idx >= total) return;
    int n  = idx >> 7;         // 128 float4 per row
    int j4 = idx & 127;
    float dv = dinv[n];
    float4 v  = ((float4*)out)[idx];
    float4 bb = ((const float4*)b)[j4];
    float4 aa = ((const float4*)alpha)[j4];
    v.x = v.x * dv + bb.x;  v.x = v.x > 0.f ? v.x : aa.x * v.x;
    v.y = v.y * dv + bb.y;  v.y = v.y > 0.f ? v.y : aa.y * v.y;
    v.z = v.z * dv + bb.z;  v.z = v.z > 0.f ? v.z : aa.z * v.z;
    v.w = v.w * dv + bb.w;  v.w = v.w > 0.f ? v.w : aa.w * v.w;
    ((float4*)out)[idx] = v;
}

extern "C" void kernel_launch(void* const* d_in, const int* in_sizes, int n_in,
                              void* d_out, int out_size, void* d_ws, size_t ws_size,
                              hipStream_t stream) {
    const float* x     = (const float*)d_in[0];
    const int*   ei    = (const int*)d_in[1];
    const float* W     = (const float*)d_in[2];
    const float* b     = (const float*)d_in[3];
    const float* alpha = (const float*)d_in[4];
    float*       out   = (float*)d_out;

    const int N = in_sizes[0] / F_IN;
    const int E = in_sizes[1] / 2;
    const int* row = ei;         // edge_index[0] = source
    const int* col = ei + E;     // edge_index[1] = target

    // Workspace layout: deg [N u32] | dinv [N f32] | (align 512KB) | hs [N*H f32]
    unsigned* deg  = (unsigned*)d_ws;
    float*    dinv = (float*)d_ws + N;
    float*    hs   = (float*)((char*)d_ws + (512u << 10));

    zero_deg_kernel<<<(N + 255) / 256, 256, 0, stream>>>(deg, N);
    count_deg_kernel<<<(E + 255) / 256, 256, 0, stream>>>(col, deg, E);
    dinv_kernel<<<(N + 255) / 256, 256, 0, stream>>>(deg, dinv, N);

    dim3 ggrid((N + 63) / 64, H_OUT / 32);
    gemm_kernel<<<ggrid, 256, 0, stream>>>(x, W, dinv, hs, out, N);

    scatter_kernel<<<(E + 3) / 4, 256, 0, stream>>>(row, col, hs, out, E);

    int total4 = N * (H_OUT / 4);
    finalize_kernel<<<(total4 + 255) / 256, 256, 0, stream>>>(out, dinv, b, alpha, N);
}

// Round 2
// 1406.940 us; speedup vs baseline: 2.7539x; 2.7539x over previous
//
#include <hip/hip_runtime.h>

// GCN encoder: h = x@W.T; symmetric-norm aggregate with self-loops; +b; PReLU.
// R2: atomics scatter -> on-device CSR build + register-accumulate gather.

#define F_IN 128
#define H_OUT 512

__global__ __launch_bounds__(256) void zero_u32_kernel(unsigned* __restrict__ p, int n) {
    int i = blockIdx.x * 256 + threadIdx.x;
    if (i < n) p[i] = 0u;
}

__global__ __launch_bounds__(256) void count_deg_kernel(const int* __restrict__ col,
                                                        unsigned* __restrict__ deg, int E) {
    int e = blockIdx.x * 256 + threadIdx.x;
    if (e < E) atomicAdd(&deg[col[e]], 1u);
}

__global__ __launch_bounds__(256) void dinv_kernel(const unsigned* __restrict__ deg,
                                                   float* __restrict__ dinv, int n) {
    int i = blockIdx.x * 256 + threadIdx.x;
    if (i < n) dinv[i] = rsqrtf((float)(deg[i] + 1u));  // +1 for self-loop
}

// Single-block exclusive scan of deg[0..n) -> rowptr[0..n], 1024 threads,
// wave-shuffle scan + 16-wave-sum scan, running carry across 1024-chunks.
__global__ __launch_bounds__(1024) void scan_kernel(const unsigned* __restrict__ deg,
                                                    int* __restrict__ rowptr, int n) {
    __shared__ unsigned wsum[16];
    const int t = threadIdx.x;
    const int lane = t & 63, wid = t >> 6;
    unsigned carry = 0;
    for (int base = 0; base < n; base += 1024) {
        unsigned v = (base + t < n) ? deg[base + t] : 0u;
        unsigned x = v;
        #pragma unroll
        for (int o = 1; o < 64; o <<= 1) {
            unsigned y = __shfl_up(x, (unsigned)o, 64);
            if (lane >= o) x += y;
        }
        if (lane == 63) wsum[wid] = x;
        __syncthreads();
        if (wid == 0 && lane < 16) {
            unsigned w = wsum[lane];
            #pragma unroll
            for (int o = 1; o < 16; o <<= 1) {
                unsigned y = __shfl_up(w, (unsigned)o, 16);
                if (lane >= o) w += y;
            }
            wsum[lane] = w;  // inclusive wave-sum scan
        }
        __syncthreads();
        unsigned prev = (wid > 0) ? wsum[wid - 1] : 0u;
        if (base + t < n) rowptr[base + t] = (int)(carry + prev + x - v);  // exclusive
        unsigned total = wsum[15];
        carry += total;
        __syncthreads();  // wsum reused next chunk
    }
    if (t == 0) rowptr[n] = (int)carry;  // == E
}

// adj[rowptr[c] + cursor[c]++] = row(e)   (cursor = re-zeroed deg array)
__global__ __launch_bounds__(256) void fill_csr_kernel(const int* __restrict__ row,
                                                       const int* __restrict__ col,
                                                       const int* __restrict__ rowptr,
                                                       unsigned* __restrict__ cursor,
                                                       int* __restrict__ adj, int E) {
    int e = blockIdx.x * 256 + threadIdx.x;
    if (e >= E) return;
    int c = col[e];
    unsigned p = atomicAdd(&cursor[c], 1u);
    adj[rowptr[c] + (int)p] = row[e];
}

// Tiled fp32 GEMM: hs[n,c] = dinv[n] * sum_k x[n,k]*W[c,k].
// Tile: 64 rows x 32 cols, 256 threads = 16(ty) x 16(tx), 4x2 outputs/thread.
__global__ __launch_bounds__(256) void gemm_kernel(const float* __restrict__ x,
                                                   const float* __restrict__ W,
                                                   const float* __restrict__ dinv,
                                                   float* __restrict__ hs, int N) {
    __shared__ float xs[64][132];
    __shared__ float ws[32][136];

    const int rb = blockIdx.x * 64;
    const int cb = blockIdx.y * 32;
    const int t  = threadIdx.x;

    #pragma unroll
    for (int i = 0; i < 8; ++i) {
        int lin = i * 256 + t;
        int r   = lin >> 5;
        int k4  = lin & 31;
        float4 v = make_float4(0.f, 0.f, 0.f, 0.f);
        if (rb + r < N) v = *(const float4*)(x + (size_t)(rb + r) * F_IN + k4 * 4);
        *(float4*)(&xs[r][k4 * 4]) = v;
    }
    #pragma unroll
    for (int i = 0; i < 4; ++i) {
        int lin = i * 256 + t;
        int r   = lin >> 5;
        int k4  = lin & 31;
        float4 v = *(const float4*)(W + (size_t)(cb + r) * F_IN + k4 * 4);
        *(float4*)(&ws[r][k4 * 4]) = v;
    }
    __syncthreads();

    const int ty = t >> 4;
    const int tx = t & 15;

    float acc[4][2] = {};
    #pragma unroll
    for (int k = 0; k < F_IN; k += 4) {
        float4 xv[4], wv[2];
        #pragma unroll
        for (int i = 0; i < 4; ++i) xv[i] = *(const float4*)(&xs[ty * 4 + i][k]);
        #pragma unroll
        for (int j = 0; j < 2; ++j) wv[j] = *(const float4*)(&ws[tx * 2 + j][k]);
        #pragma unroll
        for (int i = 0; i < 4; ++i)
            #pragma unroll
            for (int j = 0; j < 2; ++j)
                acc[i][j] += xv[i].x * wv[j].x + xv[i].y * wv[j].y +
                             xv[i].z * wv[j].z + xv[i].w * wv[j].w;
    }

    #pragma unroll
    for (int i = 0; i < 4; ++i) {
        int r = rb + ty * 4 + i;
        if (r >= N) continue;
        float dv = dinv[r];
        #pragma unroll
        for (int j = 0; j < 2; ++j) {
            int c = cb + tx * 2 + j;
            hs[(size_t)r * H_OUT + c] = acc[i][j] * dv;
        }
    }
}

// 128 threads per node (2 nodes / 256-block); thread i owns float4 slot i of
// the 512-wide row. acc = hs[self] + sum_{r in adj[node]} hs[r]; then
// out = prelu(dinv*acc + b). Each output row written exactly once - no atomics.
__global__ __launch_bounds__(256) void gather_kernel(const int* __restrict__ rowptr,
                                                     const int* __restrict__ adj,
                                                     const float* __restrict__ hs,
                                                     const float* __restrict__ dinv,
                                                     const float* __restrict__ b,
                                                     const float* __restrict__ alpha,
                                                     float* __restrict__ out, int N) {
    const int t = threadIdx.x;
    const int node = blockIdx.x * 2 + (t >> 7);
    if (node >= N) return;
    const int i = t & 127;

    const float4* hs4 = (const float4*)hs;
    float4 acc = hs4[(size_t)node * 128 + i];  // self-loop term

    const int s = rowptr[node];
    const int e = rowptr[node + 1];
    int j = s;
    for (; j + 1 < e; j += 2) {  // 2-way unroll: independent gather loads
        int r0 = adj[j];
        int r1 = adj[j + 1];
        float4 v0 = hs4[(size_t)r0 * 128 + i];
        float4 v1 = hs4[(size_t)r1 * 128 + i];
        acc.x += v0.x; acc.y += v0.y; acc.z += v0.z; acc.w += v0.w;
        acc.x += v1.x; acc.y += v1.y; acc.z += v1.z; acc.w += v1.w;
    }
    if (j < e) {
        int r0 = adj[j];
        float4 v0 = hs4[(size_t)r0 * 128 + i];
        acc.x += v0.x; acc.y += v0.y; acc.z += v0.z; acc.w += v0.w;
    }

    const float dv = dinv[node];
    float4 bb = ((const float4*)b)[i];
    float4 aa = ((const float4*)alpha)[i];
    float4 v;
    v.x = acc.x * dv + bb.x;  v.x = v.x > 0.f ? v.x : aa.x * v.x;
    v.y = acc.y * dv + bb.y;  v.y = v.y > 0.f ? v.y : aa.y * v.y;
    v.z = acc.z * dv + bb.z;  v.z = v.z > 0.f ? v.z : aa.z * v.z;
    v.w = acc.w * dv + bb.w;  v.w = v.w > 0.f ? v.w : aa.w * v.w;
    ((float4*)out)[(size_t)node * 128 + i] = v;
}

extern "C" void kernel_launch(void* const* d_in, const int* in_sizes, int n_in,
                              void* d_out, int out_size, void* d_ws, size_t ws_size,
                              hipStream_t stream) {
    const float* x     = (const float*)d_in[0];
    const int*   ei    = (const int*)d_in[1];
    const float* W     = (const float*)d_in[2];
    const float* b     = (const float*)d_in[3];
    const float* alpha = (const float*)d_in[4];
    float*       out   = (float*)d_out;

    const int N = in_sizes[0] / F_IN;
    const int E = in_sizes[1] / 2;
    const int* row = ei;         // source
    const int* col = ei + E;     // target

    // Workspace layout (bytes):
    // [0, N*H*4)                     hs
    // then deg/cursor (N u32) | dinv (N f32) | rowptr (N+1 int) | adj (E int)
    char* wsb = (char*)d_ws;
    float*    hs     = (float*)wsb;
    size_t    off    = (size_t)N * H_OUT * 4;
    unsigned* deg    = (unsigned*)(wsb + off);          off += (size_t)N * 4;
    float*    dinv   = (float*)(wsb + off);             off += (size_t)N * 4;
    int*      rowptr = (int*)(wsb + off);               off += (size_t)(N + 1) * 4;
    off = (off + 63) & ~(size_t)63;
    int*      adj    = (int*)(wsb + off);

    zero_u32_kernel<<<(N + 255) / 256, 256, 0, stream>>>(deg, N);
    count_deg_kernel<<<(E + 255) / 256, 256, 0, stream>>>(col, deg, E);
    dinv_kernel<<<(N + 255) / 256, 256, 0, stream>>>(deg, dinv, N);
    scan_kernel<<<1, 1024, 0, stream>>>(deg, rowptr, N);
    zero_u32_kernel<<<(N + 255) / 256, 256, 0, stream>>>(deg, N);  // deg -> cursor
    fill_csr_kernel<<<(E + 255) / 256, 256, 0, stream>>>(row, col, rowptr, deg, adj, E);

    dim3 ggrid((N + 63) / 64, H_OUT / 32);
    gemm_kernel<<<ggrid, 256, 0, stream>>>(x, W, dinv, hs, N);

    gather_kernel<<<(N + 1) / 2, 256, 0, stream>>>(rowptr, adj, hs, dinv, b, alpha, out, N);
}

// Round 3
// 319.233 us; speedup vs baseline: 12.1370x; 4.4073x over previous
//
#include <hip/hip_runtime.h>

// GCN encoder: h = x@W.T; symmetric-norm aggregate with self-loops; +b; PReLU.
// R3: bf16 MFMA GEMM (K=128 fully in LDS, no K-loop) + bf16 hs to halve
// gather traffic. CSR gather unchanged.

#define F_IN 128
#define H_OUT 512

typedef __bf16 bf16x8 __attribute__((ext_vector_type(8)));
typedef __bf16 bf16x4 __attribute__((ext_vector_type(4)));
typedef float  f32x4  __attribute__((ext_vector_type(4)));

__global__ __launch_bounds__(256) void zero_u32_kernel(unsigned* __restrict__ p, int n) {
    int i = blockIdx.x * 256 + threadIdx.x;
    if (i < n) p[i] = 0u;
}

__global__ __launch_bounds__(256) void count_deg_kernel(const int* __restrict__ col,
                                                        unsigned* __restrict__ deg, int E) {
    int e = blockIdx.x * 256 + threadIdx.x;
    if (e < E) atomicAdd(&deg[col[e]], 1u);
}

__global__ __launch_bounds__(256) void dinv_kernel(const unsigned* __restrict__ deg,
                                                   float* __restrict__ dinv, int n) {
    int i = blockIdx.x * 256 + threadIdx.x;
    if (i < n) dinv[i] = rsqrtf((float)(deg[i] + 1u));  // +1 for self-loop
}

// fp32 -> bf16 cast, 8 elems/thread (two float4 in, one 16B bf16x8 out).
__global__ __launch_bounds__(256) void cast_bf16_kernel(const float* __restrict__ src,
                                                        __bf16* __restrict__ dst, int n8) {
    int i = blockIdx.x * 256 + threadIdx.x;
    if (i >= n8) return;
    float4 a = ((const float4*)src)[i * 2];
    float4 b = ((const float4*)src)[i * 2 + 1];
    bf16x8 v;
    v[0] = (__bf16)a.x; v[1] = (__bf16)a.y; v[2] = (__bf16)a.z; v[3] = (__bf16)a.w;
    v[4] = (__bf16)b.x; v[5] = (__bf16)b.y; v[6] = (__bf16)b.z; v[7] = (__bf16)b.w;
    ((bf16x8*)dst)[i] = v;
}

// Single-block exclusive scan of deg[0..n) -> rowptr[0..n].
__global__ __launch_bounds__(1024) void scan_kernel(const unsigned* __restrict__ deg,
                                                    int* __restrict__ rowptr, int n) {
    __shared__ unsigned wsum[16];
    const int t = threadIdx.x;
    const int lane = t & 63, wid = t >> 6;
    unsigned carry = 0;
    for (int base = 0; base < n; base += 1024) {
        unsigned v = (base + t < n) ? deg[base + t] : 0u;
        unsigned x = v;
        #pragma unroll
        for (int o = 1; o < 64; o <<= 1) {
            unsigned y = __shfl_up(x, (unsigned)o, 64);
            if (lane >= o) x += y;
        }
        if (lane == 63) wsum[wid] = x;
        __syncthreads();
        if (wid == 0 && lane < 16) {
            unsigned w = wsum[lane];
            #pragma unroll
            for (int o = 1; o < 16; o <<= 1) {
                unsigned y = __shfl_up(w, (unsigned)o, 16);
                if (lane >= o) w += y;
            }
            wsum[lane] = w;
        }
        __syncthreads();
        unsigned prev = (wid > 0) ? wsum[wid - 1] : 0u;
        if (base + t < n) rowptr[base + t] = (int)(carry + prev + x - v);
        unsigned total = wsum[15];
        carry += total;
        __syncthreads();
    }
    if (t == 0) rowptr[n] = (int)carry;
}

__global__ __launch_bounds__(256) void fill_csr_kernel(const int* __restrict__ row,
                                                       const int* __restrict__ col,
                                                       const int* __restrict__ rowptr,
                                                       unsigned* __restrict__ cursor,
                                                       int* __restrict__ adj, int E) {
    int e = blockIdx.x * 256 + threadIdx.x;
    if (e >= E) return;
    int c = col[e];
    unsigned p = atomicAdd(&cursor[c], 1u);
    adj[rowptr[c] + (int)p] = row[e];
}

// bf16 MFMA GEMM: hs[m,n] = bf16( dinv[m] * sum_k x[m,k]*W[n,k] ).
// Tile 128x128, K=128 entirely in LDS (no K-loop). 256 thr = 4 waves;
// wave w owns rows w*32..w*32+31 (2 m-tiles), all 128 cols (8 n-tiles).
// 16x16x32 bf16 MFMA, fp32 accumulate. acc = 64 VGPR/lane, no spills.
__global__ __launch_bounds__(256) void gemm_mfma_kernel(const __bf16* __restrict__ xb,
                                                        const __bf16* __restrict__ Wb,
                                                        const float* __restrict__ dinv,
                                                        __bf16* __restrict__ hs, int N) {
    __shared__ __bf16 As[128][136];  // +8 pad: row stride 272B -> 2-way max conflict
    __shared__ __bf16 Bs[128][136];

    const int rb = blockIdx.x * 128;
    const int cb = blockIdx.y * 128;
    const int t  = threadIdx.x;

    // Stage A/B tiles: 128 rows x 16 chunks of 16B; 8 chunks/thread each.
    #pragma unroll
    for (int i = 0; i < 8; ++i) {
        int c  = i * 256 + t;        // 0..2047
        int r  = c >> 4;
        int k8 = (c & 15) * 8;
        bf16x8 v;
        #pragma unroll
        for (int j = 0; j < 8; ++j) v[j] = (__bf16)0.0f;
        if (rb + r < N) v = *(const bf16x8*)(xb + (size_t)(rb + r) * F_IN + k8);
        *(bf16x8*)&As[r][k8] = v;
    }
    #pragma unroll
    for (int i = 0; i < 8; ++i) {
        int c  = i * 256 + t;
        int r  = c >> 4;
        int k8 = (c & 15) * 8;
        bf16x8 v = *(const bf16x8*)(Wb + (size_t)(cb + r) * F_IN + k8);
        *(bf16x8*)&Bs[r][k8] = v;
    }
    __syncthreads();

    const int w    = t >> 6;
    const int lane = t & 63;
    const int lrow = lane & 15;          // operand row within 16-tile
    const int lk   = (lane >> 4) * 8;    // k-offset within 32-slice

    f32x4 acc[2][8] = {};
    #pragma unroll
    for (int ks = 0; ks < 4; ++ks) {
        const int k0 = ks * 32 + lk;
        bf16x8 a0 = *(const bf16x8*)&As[w * 32 + lrow][k0];
        bf16x8 a1 = *(const bf16x8*)&As[w * 32 + 16 + lrow][k0];
        #pragma unroll
        for (int tn = 0; tn < 8; ++tn) {
            bf16x8 bfr = *(const bf16x8*)&Bs[tn * 16 + lrow][k0];
            acc[0][tn] = __builtin_amdgcn_mfma_f32_16x16x32_bf16(a0, bfr, acc[0][tn], 0, 0, 0);
            acc[1][tn] = __builtin_amdgcn_mfma_f32_16x16x32_bf16(a1, bfr, acc[1][tn], 0, 0, 0);
        }
    }

    // C/D layout (verified m89/m91): col = lane&15, row = (lane>>4)*4 + reg.
    const int rloc = (lane >> 4) * 4;
    #pragma unroll
    for (int tm = 0; tm < 2; ++tm) {
        #pragma unroll
        for (int r = 0; r < 4; ++r) {
            int m = rb + w * 32 + tm * 16 + rloc + r;
            if (m >= N) continue;
            float dv = dinv[m];
            #pragma unroll
            for (int tn = 0; tn < 8; ++tn) {
                int n = cb + tn * 16 + lrow;
                hs[(size_t)m * H_OUT + n] = (__bf16)(acc[tm][tn][r] * dv);
            }
        }
    }
}

// 128 threads/node (2 nodes per 256-block); thread i owns bf16 cols i*4..i*4+3.
// acc(fp32) = hs[self] + sum_{r in adj} hs[r]; out = prelu(dinv*acc + b).
__global__ __launch_bounds__(256) void gather_kernel(const int* __restrict__ rowptr,
                                                     const int* __restrict__ adj,
                                                     const __bf16* __restrict__ hs,
                                                     const float* __restrict__ dinv,
                                                     const float* __restrict__ b,
                                                     const float* __restrict__ alpha,
                                                     float* __restrict__ out, int N) {
    const int t = threadIdx.x;
    const int node = blockIdx.x * 2 + (t >> 7);
    if (node >= N) return;
    const int i = t & 127;

    bf16x4 sv = *(const bf16x4*)(hs + (size_t)node * H_OUT + i * 4);
    float4 acc = make_float4((float)sv[0], (float)sv[1], (float)sv[2], (float)sv[3]);

    const int s = rowptr[node];
    const int e = rowptr[node + 1];
    int j = s;
    for (; j + 1 < e; j += 2) {
        int r0 = adj[j];
        int r1 = adj[j + 1];
        bf16x4 v0 = *(const bf16x4*)(hs + (size_t)r0 * H_OUT + i * 4);
        bf16x4 v1 = *(const bf16x4*)(hs + (size_t)r1 * H_OUT + i * 4);
        acc.x += (float)v0[0]; acc.y += (float)v0[1]; acc.z += (float)v0[2]; acc.w += (float)v0[3];
        acc.x += (float)v1[0]; acc.y += (float)v1[1]; acc.z += (float)v1[2]; acc.w += (float)v1[3];
    }
    if (j < e) {
        int r0 = adj[j];
        bf16x4 v0 = *(const bf16x4*)(hs + (size_t)r0 * H_OUT + i * 4);
        acc.x += (float)v0[0]; acc.y += (float)v0[1]; acc.z += (float)v0[2]; acc.w += (float)v0[3];
    }

    const float dv = dinv[node];
    float4 bb = ((const float4*)b)[i];
    float4 aa = ((const float4*)alpha)[i];
    float4 v;
    v.x = acc.x * dv + bb.x;  v.x = v.x > 0.f ? v.x : aa.x * v.x;
    v.y = acc.y * dv + bb.y;  v.y = v.y > 0.f ? v.y : aa.y * v.y;
    v.z = acc.z * dv + bb.z;  v.z = v.z > 0.f ? v.z : aa.z * v.z;
    v.w = acc.w * dv + bb.w;  v.w = v.w > 0.f ? v.w : aa.w * v.w;
    ((float4*)out)[(size_t)node * 128 + i] = v;
}

extern "C" void kernel_launch(void* const* d_in, const int* in_sizes, int n_in,
                              void* d_out, int out_size, void* d_ws, size_t ws_size,
                              hipStream_t stream) {
    const float* x     = (const float*)d_in[0];
    const int*   ei    = (const int*)d_in[1];
    const float* W     = (const float*)d_in[2];
    const float* b     = (const float*)d_in[3];
    const float* alpha = (const float*)d_in[4];
    float*       out   = (float*)d_out;

    const int N = in_sizes[0] / F_IN;
    const int E = in_sizes[1] / 2;
    const int* row = ei;         // source
    const int* col = ei + E;     // target

    // Workspace layout (bytes, 64B-aligned sections):
    // hs bf16 [N*512] | xb bf16 [N*128] | Wb bf16 [512*128]
    // | deg u32 [N] | dinv f32 [N] | rowptr i32 [N+1] | adj i32 [E]
    char* wsb = (char*)d_ws;
    size_t off = 0;
    __bf16* hs = (__bf16*)(wsb + off);  off += (size_t)N * H_OUT * 2;  off = (off + 63) & ~(size_t)63;
    __bf16* xb = (__bf16*)(wsb + off);  off += (size_t)N * F_IN * 2;   off = (off + 63) & ~(size_t)63;
    __bf16* Wb = (__bf16*)(wsb + off);  off += (size_t)H_OUT * F_IN * 2; off = (off + 63) & ~(size_t)63;
    unsigned* deg = (unsigned*)(wsb + off);  off += (size_t)N * 4;
    float* dinv   = (float*)(wsb + off);     off += (size_t)N * 4;
    int* rowptr   = (int*)(wsb + off);       off += (size_t)(N + 1) * 4;
    off = (off + 63) & ~(size_t)63;
    int* adj      = (int*)(wsb + off);

    int nx8 = N * F_IN / 8;
    cast_bf16_kernel<<<(nx8 + 255) / 256, 256, 0, stream>>>(x, xb, nx8);
    int nw8 = H_OUT * F_IN / 8;
    cast_bf16_kernel<<<(nw8 + 255) / 256, 256, 0, stream>>>(W, Wb, nw8);

    zero_u32_kernel<<<(N + 255) / 256, 256, 0, stream>>>(deg, N);
    count_deg_kernel<<<(E + 255) / 256, 256, 0, stream>>>(col, deg, E);
    dinv_kernel<<<(N + 255) / 256, 256, 0, stream>>>(deg, dinv, N);
    scan_kernel<<<1, 1024, 0, stream>>>(deg, rowptr, N);
    zero_u32_kernel<<<(N + 255) / 256, 256, 0, stream>>>(deg, N);  // deg -> cursor
    fill_csr_kernel<<<(E + 255) / 256, 256, 0, stream>>>(row, col, rowptr, deg, adj, E);

    dim3 ggrid((N + 127) / 128, H_OUT / 128);
    gemm_mfma_kernel<<<ggrid, 256, 0, stream>>>(xb, Wb, dinv, hs, N);

    gather_kernel<<<(N + 1) / 2, 256, 0, stream>>>(rowptr, adj, hs, dinv, b, alpha, out, N);
}

// Round 4
// 272.629 us; speedup vs baseline: 14.2117x; 1.1709x over previous
//
#include <hip/hip_runtime.h>

// GCN encoder: h = x@W.T; symmetric-norm aggregate with self-loops; +b; PReLU.
// R4: hierarchical scan (was single-block = single-CU, ~100us serial tail),
// dinv/cursor-zero fused into scan-apply, wave-per-node bf16x8 gather.

#define F_IN 128
#define H_OUT 512

typedef __bf16 bf16x8 __attribute__((ext_vector_type(8)));
typedef float  f32x4  __attribute__((ext_vector_type(4)));

// fp32 -> bf16 cast, 8 elems/thread.
__global__ __launch_bounds__(256) void cast_bf16_kernel(const float* __restrict__ src,
                                                        __bf16* __restrict__ dst, int n8) {
    int i = blockIdx.x * 256 + threadIdx.x;
    if (i >= n8) return;
    float4 a = ((const float4*)src)[i * 2];
    float4 b = ((const float4*)src)[i * 2 + 1];
    bf16x8 v;
    v[0] = (__bf16)a.x; v[1] = (__bf16)a.y; v[2] = (__bf16)a.z; v[3] = (__bf16)a.w;
    v[4] = (__bf16)b.x; v[5] = (__bf16)b.y; v[6] = (__bf16)b.z; v[7] = (__bf16)b.w;
    ((bf16x8*)dst)[i] = v;
}

__global__ __launch_bounds__(256) void count_deg_kernel(const int* __restrict__ col,
                                                        unsigned* __restrict__ deg, int E) {
    int e = blockIdx.x * 256 + threadIdx.x;
    if (e < E) atomicAdd(&deg[col[e]], 1u);
}

// Stage 1: block b sums deg[b*1024 .. b*1024+1024) -> partial[b].
__global__ __launch_bounds__(256) void deg_reduce_kernel(const unsigned* __restrict__ deg,
                                                         unsigned* __restrict__ partial, int n) {
    __shared__ unsigned wsum[4];
    const int t = threadIdx.x;
    const int i0 = blockIdx.x * 1024 + t * 4;
    unsigned s = 0;
    if (i0 + 3 < n) {
        uint4 v = *(const uint4*)(deg + i0);
        s = v.x + v.y + v.z + v.w;
    } else {
        #pragma unroll
        for (int j = 0; j < 4; ++j) if (i0 + j < n) s += deg[i0 + j];
    }
    #pragma unroll
    for (int o = 32; o > 0; o >>= 1) s += __shfl_down(s, (unsigned)o, 64);
    if ((t & 63) == 0) wsum[t >> 6] = s;
    __syncthreads();
    if (t == 0) partial[blockIdx.x] = wsum[0] + wsum[1] + wsum[2] + wsum[3];
}

// Stage 2: one wave scans nb (<=64) partials -> exclusive offs.
__global__ __launch_bounds__(64) void scan_partials_kernel(const unsigned* __restrict__ partial,
                                                           unsigned* __restrict__ offs, int nb) {
    const int t = threadIdx.x;
    unsigned v = (t < nb) ? partial[t] : 0u;
    unsigned x = v;
    #pragma unroll
    for (int o = 1; o < 64; o <<= 1) {
        unsigned y = __shfl_up(x, (unsigned)o, 64);
        if (t >= o) x += y;
    }
    if (t < nb) offs[t] = x - v;
}

// Stage 3: block b rescans its 1024 deg values -> rowptr; fused dinv + cursor=0.
__global__ __launch_bounds__(256) void scan_apply_kernel(const unsigned* __restrict__ deg,
                                                         const unsigned* __restrict__ offs,
                                                         int* __restrict__ rowptr,
                                                         float* __restrict__ dinv,
                                                         unsigned* __restrict__ cursor,
                                                         int n, int E) {
    __shared__ unsigned wsum[4];
    const int t = threadIdx.x, lane = t & 63, wid = t >> 6;
    const int i0 = blockIdx.x * 1024 + t * 4;
    unsigned d[4] = {0u, 0u, 0u, 0u};
    if (i0 + 3 < n) {
        uint4 v = *(const uint4*)(deg + i0);
        d[0] = v.x; d[1] = v.y; d[2] = v.z; d[3] = v.w;
    } else {
        #pragma unroll
        for (int j = 0; j < 4; ++j) if (i0 + j < n) d[j] = deg[i0 + j];
    }
    unsigned s = d[0] + d[1] + d[2] + d[3];
    unsigned x = s;
    #pragma unroll
    for (int o = 1; o < 64; o <<= 1) {
        unsigned y = __shfl_up(x, (unsigned)o, 64);
        if (lane >= o) x += y;
    }
    if (lane == 63) wsum[wid] = x;
    __syncthreads();
    unsigned wprev = 0;
    for (int q = 0; q < wid; ++q) wprev += wsum[q];
    unsigned base = offs[blockIdx.x] + wprev + (x - s);  // exclusive thread base
    unsigned run = 0;
    #pragma unroll
    for (int j = 0; j < 4; ++j) {
        int i = i0 + j;
        if (i < n) {
            rowptr[i] = (int)(base + run);
            dinv[i]   = rsqrtf((float)(d[j] + 1u));  // +1 self-loop
            cursor[i] = 0u;
        }
        run += d[j];
    }
    if (blockIdx.x == 0 && t == 0) rowptr[n] = E;
}

__global__ __launch_bounds__(256) void fill_csr_kernel(const int* __restrict__ row,
                                                       const int* __restrict__ col,
                                                       const int* __restrict__ rowptr,
                                                       unsigned* __restrict__ cursor,
                                                       int* __restrict__ adj, int E) {
    int e = blockIdx.x * 256 + threadIdx.x;
    if (e >= E) return;
    int c = col[e];
    unsigned p = atomicAdd(&cursor[c], 1u);
    adj[rowptr[c] + (int)p] = row[e];
}

// bf16 MFMA GEMM: hs[m,n] = bf16( dinv[m] * sum_k x[m,k]*W[n,k] ).
// 128x128 tile, K=128 entirely in LDS, 4 waves x (2 m-tiles x 8 n-tiles).
__global__ __launch_bounds__(256) void gemm_mfma_kernel(const __bf16* __restrict__ xb,
                                                        const __bf16* __restrict__ Wb,
                                                        const float* __restrict__ dinv,
                                                        __bf16* __restrict__ hs, int N) {
    __shared__ __bf16 As[128][136];  // +8 pad
    __shared__ __bf16 Bs[128][136];

    const int rb = blockIdx.x * 128;
    const int cb = blockIdx.y * 128;
    const int t  = threadIdx.x;

    #pragma unroll
    for (int i = 0; i < 8; ++i) {
        int c  = i * 256 + t;
        int r  = c >> 4;
        int k8 = (c & 15) * 8;
        bf16x8 v;
        #pragma unroll
        for (int j = 0; j < 8; ++j) v[j] = (__bf16)0.0f;
        if (rb + r < N) v = *(const bf16x8*)(xb + (size_t)(rb + r) * F_IN + k8);
        *(bf16x8*)&As[r][k8] = v;
    }
    #pragma unroll
    for (int i = 0; i < 8; ++i) {
        int c  = i * 256 + t;
        int r  = c >> 4;
        int k8 = (c & 15) * 8;
        bf16x8 v = *(const bf16x8*)(Wb + (size_t)(cb + r) * F_IN + k8);
        *(bf16x8*)&Bs[r][k8] = v;
    }
    __syncthreads();

    const int w    = t >> 6;
    const int lane = t & 63;
    const int lrow = lane & 15;
    const int lk   = (lane >> 4) * 8;

    f32x4 acc[2][8] = {};
    #pragma unroll
    for (int ks = 0; ks < 4; ++ks) {
        const int k0 = ks * 32 + lk;
        bf16x8 a0 = *(const bf16x8*)&As[w * 32 + lrow][k0];
        bf16x8 a1 = *(const bf16x8*)&As[w * 32 + 16 + lrow][k0];
        #pragma unroll
        for (int tn = 0; tn < 8; ++tn) {
            bf16x8 bfr = *(const bf16x8*)&Bs[tn * 16 + lrow][k0];
            acc[0][tn] = __builtin_amdgcn_mfma_f32_16x16x32_bf16(a0, bfr, acc[0][tn], 0, 0, 0);
            acc[1][tn] = __builtin_amdgcn_mfma_f32_16x16x32_bf16(a1, bfr, acc[1][tn], 0, 0, 0);
        }
    }

    // C/D layout: col = lane&15, row = (lane>>4)*4 + reg.
    const int rloc = (lane >> 4) * 4;
    #pragma unroll
    for (int tm = 0; tm < 2; ++tm) {
        #pragma unroll
        for (int r = 0; r < 4; ++r) {
            int m = rb + w * 32 + tm * 16 + rloc + r;
            if (m >= N) continue;
            float dv = dinv[m];
            #pragma unroll
            for (int tn = 0; tn < 8; ++tn) {
                int n = cb + tn * 16 + lrow;
                hs[(size_t)m * H_OUT + n] = (__bf16)(acc[tm][tn][r] * dv);
            }
        }
    }
}

// One wave per node; lane owns bf16x8 chunk (cols lane*8..lane*8+7, 16B load).
// acc(fp32) = hs[self] + sum_{r in adj} hs[r]; out = prelu(dinv*acc + b).
__global__ __launch_bounds__(256) void gather_kernel(const int* __restrict__ rowptr,
                                                     const int* __restrict__ adj,
                                                     const __bf16* __restrict__ hs,
                                                     const float* __restrict__ dinv,
                                                     const float* __restrict__ bias,
                                                     const float* __restrict__ alpha,
                                                     float* __restrict__ out, int N) {
    const int wv = threadIdx.x >> 6, lane = threadIdx.x & 63;
    const int node = blockIdx.x * 4 + wv;
    if (node >= N) return;

    const bf16x8* hs8 = (const bf16x8*)hs;  // 64 chunks per row
    bf16x8 sv = hs8[(size_t)node * 64 + lane];
    float acc[8];
    #pragma unroll
    for (int q = 0; q < 8; ++q) acc[q] = (float)sv[q];

    const int s = rowptr[node];
    const int e = rowptr[node + 1];
    int j = s;
    for (; j + 1 < e; j += 2) {
        int r0 = adj[j];
        int r1 = adj[j + 1];
        bf16x8 v0 = hs8[(size_t)r0 * 64 + lane];
        bf16x8 v1 = hs8[(size_t)r1 * 64 + lane];
        #pragma unroll
        for (int q = 0; q < 8; ++q) acc[q] += (float)v0[q] + (float)v1[q];
    }
    if (j < e) {
        int r0 = adj[j];
        bf16x8 v0 = hs8[(size_t)r0 * 64 + lane];
        #pragma unroll
        for (int q = 0; q < 8; ++q) acc[q] += (float)v0[q];
    }

    const float dv = dinv[node];
    const float4* b4 = (const float4*)bias;
    const float4* a4 = (const float4*)alpha;
    float4 bb0 = b4[lane * 2], bb1 = b4[lane * 2 + 1];
    float4 aa0 = a4[lane * 2], aa1 = a4[lane * 2 + 1];
    float4 o0, o1;
    o0.x = acc[0] * dv + bb0.x;  o0.x = o0.x > 0.f ? o0.x : aa0.x * o0.x;
    o0.y = acc[1] * dv + bb0.y;  o0.y = o0.y > 0.f ? o0.y : aa0.y * o0.y;
    o0.z = acc[2] * dv + bb0.z;  o0.z = o0.z > 0.f ? o0.z : aa0.z * o0.z;
    o0.w = acc[3] * dv + bb0.w;  o0.w = o0.w > 0.f ? o0.w : aa0.w * o0.w;
    o1.x = acc[4] * dv + bb1.x;  o1.x = o1.x > 0.f ? o1.x : aa1.x * o1.x;
    o1.y = acc[5] * dv + bb1.y;  o1.y = o1.y > 0.f ? o1.y : aa1.y * o1.y;
    o1.z = acc[6] * dv + bb1.z;  o1.z = o1.z > 0.f ? o1.z : aa1.z * o1.z;
    o1.w = acc[7] * dv + bb1.w;  o1.w = o1.w > 0.f ? o1.w : aa1.w * o1.w;
    float4* orow = (float4*)(out + (size_t)node * H_OUT);
    orow[lane * 2]     = o0;
    orow[lane * 2 + 1] = o1;
}

extern "C" void kernel_launch(void* const* d_in, const int* in_sizes, int n_in,
                              void* d_out, int out_size, void* d_ws, size_t ws_size,
                              hipStream_t stream) {
    const float* x     = (const float*)d_in[0];
    const int*   ei    = (const int*)d_in[1];
    const float* W     = (const float*)d_in[2];
    const float* b     = (const float*)d_in[3];
    const float* alpha = (const float*)d_in[4];
    float*       out   = (float*)d_out;

    const int N = in_sizes[0] / F_IN;
    const int E = in_sizes[1] / 2;
    const int* row = ei;         // source
    const int* col = ei + E;     // target
    const int NB = (N + 1023) / 1024;  // scan blocks (49 for N=50000)

    // Workspace layout (64B-aligned sections).
    char* wsb = (char*)d_ws;
    size_t off = 0;
    __bf16* hs = (__bf16*)(wsb + off);  off += (size_t)N * H_OUT * 2;    off = (off + 63) & ~(size_t)63;
    __bf16* xb = (__bf16*)(wsb + off);  off += (size_t)N * F_IN * 2;     off = (off + 63) & ~(size_t)63;
    __bf16* Wb = (__bf16*)(wsb + off);  off += (size_t)H_OUT * F_IN * 2; off = (off + 63) & ~(size_t)63;
    unsigned* deg    = (unsigned*)(wsb + off);  off += (size_t)N * 4;
    unsigned* cursor = (unsigned*)(wsb + off);  off += (size_t)N * 4;
    float*    dinv   = (float*)(wsb + off);     off += (size_t)N * 4;
    int*      rowptr = (int*)(wsb + off);       off += (size_t)(N + 1) * 4;
    off = (off + 63) & ~(size_t)63;
    unsigned* partial = (unsigned*)(wsb + off); off += (size_t)NB * 4;
    unsigned* offs    = (unsigned*)(wsb + off); off += (size_t)NB * 4;
    off = (off + 63) & ~(size_t)63;
    int* adj = (int*)(wsb + off);

    hipMemsetAsync(deg, 0, (size_t)N * 4, stream);

    int nx8 = N * F_IN / 8;
    cast_bf16_kernel<<<(nx8 + 255) / 256, 256, 0, stream>>>(x, xb, nx8);
    int nw8 = H_OUT * F_IN / 8;
    cast_bf16_kernel<<<(nw8 + 255) / 256, 256, 0, stream>>>(W, Wb, nw8);

    count_deg_kernel<<<(E + 255) / 256, 256, 0, stream>>>(col, deg, E);
    deg_reduce_kernel<<<NB, 256, 0, stream>>>(deg, partial, N);
    scan_partials_kernel<<<1, 64, 0, stream>>>(partial, offs, NB);
    scan_apply_kernel<<<NB, 256, 0, stream>>>(deg, offs, rowptr, dinv, cursor, N, E);
    fill_csr_kernel<<<(E + 255) / 256, 256, 0, stream>>>(row, col, rowptr, cursor, adj, E);

    dim3 ggrid((N + 127) / 128, H_OUT / 128);
    gemm_mfma_kernel<<<ggrid, 256, 0, stream>>>(xb, Wb, dinv, hs, N);

    gather_kernel<<<(N + 3) / 4, 256, 0, stream>>>(rowptr, adj, hs, dinv, b, alpha, out, N);
}

// Round 5
// 220.142 us; speedup vs baseline: 17.6002x; 1.2384x over previous
//
#include <hip/hip_runtime.h>

// GCN encoder: out = prelu( (Dinv A_hat Dinv X) W^T + b ).
// R5: aggregate-then-transform. Gather runs on X (128 cols, 12.8 MB bf16)
// instead of h (512 cols, 51 MB) -- 4x less gather traffic, hs eliminated.

#define F_IN 128
#define H_OUT 512

typedef __bf16 bf16x8 __attribute__((ext_vector_type(8)));
typedef float  f32x4  __attribute__((ext_vector_type(4)));

// plain fp32 -> bf16 cast, 8 elems/thread (for W).
__global__ __launch_bounds__(256) void cast_bf16_kernel(const float* __restrict__ src,
                                                        __bf16* __restrict__ dst, int n8) {
    int i = blockIdx.x * 256 + threadIdx.x;
    if (i >= n8) return;
    float4 a = ((const float4*)src)[i * 2];
    float4 b = ((const float4*)src)[i * 2 + 1];
    bf16x8 v;
    v[0] = (__bf16)a.x; v[1] = (__bf16)a.y; v[2] = (__bf16)a.z; v[3] = (__bf16)a.w;
    v[4] = (__bf16)b.x; v[5] = (__bf16)b.y; v[6] = (__bf16)b.z; v[7] = (__bf16)b.w;
    ((bf16x8*)dst)[i] = v;
}

// xs[i,:] = bf16( dinv[i] * x[i,:] ), 8 elems/thread (one node row = 16 thr).
__global__ __launch_bounds__(256) void scale_cast_kernel(const float* __restrict__ x,
                                                         const float* __restrict__ dinv,
                                                         __bf16* __restrict__ xs, int n8) {
    int i = blockIdx.x * 256 + threadIdx.x;
    if (i >= n8) return;
    float dv = dinv[i >> 4];   // 16 bf16x8 chunks per 128-col row
    float4 a = ((const float4*)x)[i * 2];
    float4 b = ((const float4*)x)[i * 2 + 1];
    bf16x8 v;
    v[0] = (__bf16)(a.x * dv); v[1] = (__bf16)(a.y * dv);
    v[2] = (__bf16)(a.z * dv); v[3] = (__bf16)(a.w * dv);
    v[4] = (__bf16)(b.x * dv); v[5] = (__bf16)(b.y * dv);
    v[6] = (__bf16)(b.z * dv); v[7] = (__bf16)(b.w * dv);
    ((bf16x8*)xs)[i] = v;
}

__global__ __launch_bounds__(256) void count_deg_kernel(const int* __restrict__ col,
                                                        unsigned* __restrict__ deg, int E) {
    int e = blockIdx.x * 256 + threadIdx.x;
    if (e < E) atomicAdd(&deg[col[e]], 1u);
}

// Stage 1: block b sums deg[b*1024 .. b*1024+1024) -> partial[b].
__global__ __launch_bounds__(256) void deg_reduce_kernel(const unsigned* __restrict__ deg,
                                                         unsigned* __restrict__ partial, int n) {
    __shared__ unsigned wsum[4];
    const int t = threadIdx.x;
    const int i0 = blockIdx.x * 1024 + t * 4;
    unsigned s = 0;
    if (i0 + 3 < n) {
        uint4 v = *(const uint4*)(deg + i0);
        s = v.x + v.y + v.z + v.w;
    } else {
        #pragma unroll
        for (int j = 0; j < 4; ++j) if (i0 + j < n) s += deg[i0 + j];
    }
    #pragma unroll
    for (int o = 32; o > 0; o >>= 1) s += __shfl_down(s, (unsigned)o, 64);
    if ((t & 63) == 0) wsum[t >> 6] = s;
    __syncthreads();
    if (t == 0) partial[blockIdx.x] = wsum[0] + wsum[1] + wsum[2] + wsum[3];
}

// Stage 2: one wave scans nb (<=64) partials -> exclusive offs.
__global__ __launch_bounds__(64) void scan_partials_kernel(const unsigned* __restrict__ partial,
                                                           unsigned* __restrict__ offs, int nb) {
    const int t = threadIdx.x;
    unsigned v = (t < nb) ? partial[t] : 0u;
    unsigned x = v;
    #pragma unroll
    for (int o = 1; o < 64; o <<= 1) {
        unsigned y = __shfl_up(x, (unsigned)o, 64);
        if (t >= o) x += y;
    }
    if (t < nb) offs[t] = x - v;
}

// Stage 3: rescan 1024 deg/block -> rowptr; fused dinv + cursor=0.
__global__ __launch_bounds__(256) void scan_apply_kernel(const unsigned* __restrict__ deg,
                                                         const unsigned* __restrict__ offs,
                                                         int* __restrict__ rowptr,
                                                         float* __restrict__ dinv,
                                                         unsigned* __restrict__ cursor,
                                                         int n, int E) {
    __shared__ unsigned wsum[4];
    const int t = threadIdx.x, lane = t & 63, wid = t >> 6;
    const int i0 = blockIdx.x * 1024 + t * 4;
    unsigned d[4] = {0u, 0u, 0u, 0u};
    if (i0 + 3 < n) {
        uint4 v = *(const uint4*)(deg + i0);
        d[0] = v.x; d[1] = v.y; d[2] = v.z; d[3] = v.w;
    } else {
        #pragma unroll
        for (int j = 0; j < 4; ++j) if (i0 + j < n) d[j] = deg[i0 + j];
    }
    unsigned s = d[0] + d[1] + d[2] + d[3];
    unsigned x = s;
    #pragma unroll
    for (int o = 1; o < 64; o <<= 1) {
        unsigned y = __shfl_up(x, (unsigned)o, 64);
        if (lane >= o) x += y;
    }
    if (lane == 63) wsum[wid] = x;
    __syncthreads();
    unsigned wprev = 0;
    for (int q = 0; q < wid; ++q) wprev += wsum[q];
    unsigned base = offs[blockIdx.x] + wprev + (x - s);
    unsigned run = 0;
    #pragma unroll
    for (int j = 0; j < 4; ++j) {
        int i = i0 + j;
        if (i < n) {
            rowptr[i] = (int)(base + run);
            dinv[i]   = rsqrtf((float)(d[j] + 1u));  // +1 self-loop
            cursor[i] = 0u;
        }
        run += d[j];
    }
    if (blockIdx.x == 0 && t == 0) rowptr[n] = E;
}

__global__ __launch_bounds__(256) void fill_csr_kernel(const int* __restrict__ row,
                                                       const int* __restrict__ col,
                                                       const int* __restrict__ rowptr,
                                                       unsigned* __restrict__ cursor,
                                                       int* __restrict__ adj, int E) {
    int e = blockIdx.x * 256 + threadIdx.x;
    if (e >= E) return;
    int c = col[e];
    unsigned p = atomicAdd(&cursor[c], 1u);
    adj[rowptr[c] + (int)p] = row[e];
}

// Aggregate: ag[c,:] = bf16( dinv[c] * ( xs[c,:] + sum_{r in adj[c]} xs[r,:] ) ).
// 16 lanes per node (16 x bf16x8 = 256 B row), 4 independent nodes per wave.
__global__ __launch_bounds__(256) void gather_agg_kernel(const int* __restrict__ rowptr,
                                                         const int* __restrict__ adj,
                                                         const __bf16* __restrict__ xs,
                                                         const float* __restrict__ dinv,
                                                         __bf16* __restrict__ ag, int N) {
    const int t = threadIdx.x;
    const int node = blockIdx.x * 16 + (t >> 4);
    if (node >= N) return;
    const int li = t & 15;

    const bf16x8* xs8 = (const bf16x8*)xs;  // 16 chunks per row
    bf16x8 sv = xs8[(size_t)node * 16 + li];
    float acc[8];
    #pragma unroll
    for (int q = 0; q < 8; ++q) acc[q] = (float)sv[q];

    const int s = rowptr[node];
    const int e = rowptr[node + 1];
    int j = s;
    for (; j + 3 < e; j += 4) {      // 4-way unroll: independent gather chains
        int r0 = adj[j], r1 = adj[j + 1], r2 = adj[j + 2], r3 = adj[j + 3];
        bf16x8 v0 = xs8[(size_t)r0 * 16 + li];
        bf16x8 v1 = xs8[(size_t)r1 * 16 + li];
        bf16x8 v2 = xs8[(size_t)r2 * 16 + li];
        bf16x8 v3 = xs8[(size_t)r3 * 16 + li];
        #pragma unroll
        for (int q = 0; q < 8; ++q)
            acc[q] += ((float)v0[q] + (float)v1[q]) + ((float)v2[q] + (float)v3[q]);
    }
    for (; j < e; ++j) {
        int r0 = adj[j];
        bf16x8 v0 = xs8[(size_t)r0 * 16 + li];
        #pragma unroll
        for (int q = 0; q < 8; ++q) acc[q] += (float)v0[q];
    }

    const float dv = dinv[node];
    bf16x8 o;
    #pragma unroll
    for (int q = 0; q < 8; ++q) o[q] = (__bf16)(acc[q] * dv);
    ((bf16x8*)ag)[(size_t)node * 16 + li] = o;
}

// bf16 MFMA GEMM: out[m,n] = prelu( sum_k ag[m,k]*W[n,k] + b[n] ), fp32 out.
// 128x128 tile, K=128 entirely in LDS, 4 waves x (2 m-tiles x 8 n-tiles).
__global__ __launch_bounds__(256) void gemm_mfma_kernel(const __bf16* __restrict__ ag,
                                                        const __bf16* __restrict__ Wb,
                                                        const float* __restrict__ bias,
                                                        const float* __restrict__ alpha,
                                                        float* __restrict__ out, int N) {
    __shared__ __bf16 As[128][136];  // +8 pad
    __shared__ __bf16 Bs[128][136];

    const int rb = blockIdx.x * 128;
    const int cb = blockIdx.y * 128;
    const int t  = threadIdx.x;

    #pragma unroll
    for (int i = 0; i < 8; ++i) {
        int c  = i * 256 + t;
        int r  = c >> 4;
        int k8 = (c & 15) * 8;
        bf16x8 v;
        #pragma unroll
        for (int j = 0; j < 8; ++j) v[j] = (__bf16)0.0f;
        if (rb + r < N) v = *(const bf16x8*)(ag + (size_t)(rb + r) * F_IN + k8);
        *(bf16x8*)&As[r][k8] = v;
    }
    #pragma unroll
    for (int i = 0; i < 8; ++i) {
        int c  = i * 256 + t;
        int r  = c >> 4;
        int k8 = (c & 15) * 8;
        bf16x8 v = *(const bf16x8*)(Wb + (size_t)(cb + r) * F_IN + k8);
        *(bf16x8*)&Bs[r][k8] = v;
    }
    __syncthreads();

    const int w    = t >> 6;
    const int lane = t & 63;
    const int lrow = lane & 15;
    const int lk   = (lane >> 4) * 8;

    f32x4 acc[2][8] = {};
    #pragma unroll
    for (int ks = 0; ks < 4; ++ks) {
        const int k0 = ks * 32 + lk;
        bf16x8 a0 = *(const bf16x8*)&As[w * 32 + lrow][k0];
        bf16x8 a1 = *(const bf16x8*)&As[w * 32 + 16 + lrow][k0];
        #pragma unroll
        for (int tn = 0; tn < 8; ++tn) {
            bf16x8 bfr = *(const bf16x8*)&Bs[tn * 16 + lrow][k0];
            acc[0][tn] = __builtin_amdgcn_mfma_f32_16x16x32_bf16(a0, bfr, acc[0][tn], 0, 0, 0);
            acc[1][tn] = __builtin_amdgcn_mfma_f32_16x16x32_bf16(a1, bfr, acc[1][tn], 0, 0, 0);
        }
    }

    // Epilogue: bias + PReLU per column; C/D layout col=lane&15, row=(lane>>4)*4+reg.
    float bb[8], aa[8];
    #pragma unroll
    for (int tn = 0; tn < 8; ++tn) {
        int n = cb + tn * 16 + lrow;
        bb[tn] = bias[n];
        aa[tn] = alpha[n];
    }
    const int rloc = (lane >> 4) * 4;
    #pragma unroll
    for (int tm = 0; tm < 2; ++tm) {
        #pragma unroll
        for (int r = 0; r < 4; ++r) {
            int m = rb + w * 32 + tm * 16 + rloc + r;
            if (m >= N) continue;
            #pragma unroll
            for (int tn = 0; tn < 8; ++tn) {
                int n = cb + tn * 16 + lrow;
                float v = acc[tm][tn][r] + bb[tn];
                v = v > 0.f ? v : aa[tn] * v;
                out[(size_t)m * H_OUT + n] = v;
            }
        }
    }
}

extern "C" void kernel_launch(void* const* d_in, const int* in_sizes, int n_in,
                              void* d_out, int out_size, void* d_ws, size_t ws_size,
                              hipStream_t stream) {
    const float* x     = (const float*)d_in[0];
    const int*   ei    = (const int*)d_in[1];
    const float* W     = (const float*)d_in[2];
    const float* b     = (const float*)d_in[3];
    const float* alpha = (const float*)d_in[4];
    float*       out   = (float*)d_out;

    const int N = in_sizes[0] / F_IN;
    const int E = in_sizes[1] / 2;
    const int* row = ei;         // source
    const int* col = ei + E;     // target
    const int NB = (N + 1023) / 1024;

    // Workspace layout (64B-aligned sections).
    char* wsb = (char*)d_ws;
    size_t off = 0;
    __bf16* xs = (__bf16*)(wsb + off);  off += (size_t)N * F_IN * 2;     off = (off + 63) & ~(size_t)63;
    __bf16* ag = (__bf16*)(wsb + off);  off += (size_t)N * F_IN * 2;     off = (off + 63) & ~(size_t)63;
    __bf16* Wb = (__bf16*)(wsb + off);  off += (size_t)H_OUT * F_IN * 2; off = (off + 63) & ~(size_t)63;
    unsigned* deg    = (unsigned*)(wsb + off);  off += (size_t)N * 4;
    unsigned* cursor = (unsigned*)(wsb + off);  off += (size_t)N * 4;
    float*    dinv   = (float*)(wsb + off);     off += (size_t)N * 4;
    int*      rowptr = (int*)(wsb + off);       off += (size_t)(N + 1) * 4;
    off = (off + 63) & ~(size_t)63;
    unsigned* partial = (unsigned*)(wsb + off); off += (size_t)NB * 4;
    unsigned* offs    = (unsigned*)(wsb + off); off += (size_t)NB * 4;
    off = (off + 63) & ~(size_t)63;
    int* adj = (int*)(wsb + off);

    hipMemsetAsync(deg, 0, (size_t)N * 4, stream);

    int nw8 = H_OUT * F_IN / 8;
    cast_bf16_kernel<<<(nw8 + 255) / 256, 256, 0, stream>>>(W, Wb, nw8);

    count_deg_kernel<<<(E + 255) / 256, 256, 0, stream>>>(col, deg, E);
    deg_reduce_kernel<<<NB, 256, 0, stream>>>(deg, partial, N);
    scan_partials_kernel<<<1, 64, 0, stream>>>(partial, offs, NB);
    scan_apply_kernel<<<NB, 256, 0, stream>>>(deg, offs, rowptr, dinv, cursor, N, E);
    fill_csr_kernel<<<(E + 255) / 256, 256, 0, stream>>>(row, col, rowptr, cursor, adj, E);

    int nx8 = N * F_IN / 8;
    scale_cast_kernel<<<(nx8 + 255) / 256, 256, 0, stream>>>(x, dinv, xs, nx8);

    gather_agg_kernel<<<(N + 15) / 16, 256, 0, stream>>>(rowptr, adj, xs, dinv, ag, N);

    dim3 ggrid((N + 127) / 128, H_OUT / 128);
    gemm_mfma_kernel<<<ggrid, 256, 0, stream>>>(ag, Wb, b, alpha, out, N);
}

// Round 6
// 219.495 us; speedup vs baseline: 17.6520x; 1.0029x over previous
//
#include <hip/hip_runtime.h>

// GCN encoder: out = prelu( (Dinv A_hat Dinv X) W^T + b ).
// R6: launch-count collapse (11 -> 6 graph nodes). Order-free CSR segment
// assignment via wave-aggregated atomic cursor kills the 3-stage scan;
// prep (cast W, cast X, count deg) fused into one multi-role kernel;
// per-edge dinv weighting in gather removes the scale pass.

#define F_IN 128
#define H_OUT 512

typedef __bf16 bf16x8 __attribute__((ext_vector_type(8)));
typedef float  f32x4  __attribute__((ext_vector_type(4)));

// Multi-role prep: blocks [0,NWB) cast W->bf16; [NWB,NWB+NXB) cast x->bf16
// (unscaled); rest count in-degrees with atomics. All edge-independent work
// in one launch.
__global__ __launch_bounds__(256) void prep_kernel(const float* __restrict__ W,
                                                   __bf16* __restrict__ Wb, int nw8,
                                                   const float* __restrict__ x,
                                                   __bf16* __restrict__ xs, int nx8,
                                                   const int* __restrict__ col,
                                                   unsigned* __restrict__ deg, int E,
                                                   int NWB, int NXB) {
    const int b = blockIdx.x, t = threadIdx.x;
    if (b < NWB) {
        int i = b * 256 + t;
        if (i >= nw8) return;
        float4 a0 = ((const float4*)W)[i * 2];
        float4 a1 = ((const float4*)W)[i * 2 + 1];
        bf16x8 v;
        v[0] = (__bf16)a0.x; v[1] = (__bf16)a0.y; v[2] = (__bf16)a0.z; v[3] = (__bf16)a0.w;
        v[4] = (__bf16)a1.x; v[5] = (__bf16)a1.y; v[6] = (__bf16)a1.z; v[7] = (__bf16)a1.w;
        ((bf16x8*)Wb)[i] = v;
    } else if (b < NWB + NXB) {
        int i = (b - NWB) * 256 + t;
        if (i >= nx8) return;
        float4 a0 = ((const float4*)x)[i * 2];
        float4 a1 = ((const float4*)x)[i * 2 + 1];
        bf16x8 v;
        v[0] = (__bf16)a0.x; v[1] = (__bf16)a0.y; v[2] = (__bf16)a0.z; v[3] = (__bf16)a0.w;
        v[4] = (__bf16)a1.x; v[5] = (__bf16)a1.y; v[6] = (__bf16)a1.z; v[7] = (__bf16)a1.w;
        ((bf16x8*)xs)[i] = v;
    } else {
        int e = (b - NWB - NXB) * 256 + t;
        if (e < E) atomicAdd(&deg[col[e]], 1u);
    }
}

// Order-free CSR segment assignment: wave-scan deg, one atomicAdd on the
// global cursor per wave, distribute. rowptr[c]=cursor[c]=segment start;
// dinv[c]=rsqrt(deg+1). (Segment order in adj is arbitrary -- gather only
// needs [rowptr[c], rowptr[c]+deg[c]).)
__global__ __launch_bounds__(256) void assign_kernel(const unsigned* __restrict__ deg,
                                                     unsigned* __restrict__ total,
                                                     int* __restrict__ rowptr,
                                                     unsigned* __restrict__ cursor,
                                                     float* __restrict__ dinv, int n) {
    const int i = blockIdx.x * 256 + threadIdx.x;
    const int lane = threadIdx.x & 63;
    unsigned d = (i < n) ? deg[i] : 0u;
    unsigned x = d;
    #pragma unroll
    for (int o = 1; o < 64; o <<= 1) {
        unsigned y = __shfl_up(x, (unsigned)o, 64);
        if (lane >= o) x += y;
    }
    unsigned tot = __shfl(x, 63, 64);       // wave total
    unsigned wb = 0;
    if (lane == 63) wb = atomicAdd(total, tot);
    wb = __shfl(wb, 63, 64);                // wave base
    if (i < n) {
        unsigned start = wb + x - d;        // exclusive within wave
        rowptr[i] = (int)start;
        cursor[i] = start;
        dinv[i]   = rsqrtf((float)(d + 1u));  // +1 self-loop
    }
}

// adj[cursor[c]++] = row(e); after completion cursor[c] == segment end.
__global__ __launch_bounds__(256) void fill_csr_kernel(const int* __restrict__ row,
                                                       const int* __restrict__ col,
                                                       unsigned* __restrict__ cursor,
                                                       int* __restrict__ adj, int E) {
    int e = blockIdx.x * 256 + threadIdx.x;
    if (e >= E) return;
    unsigned p = atomicAdd(&cursor[col[e]], 1u);
    adj[p] = row[e];
}

// Aggregate: ag[c,:] = bf16( dinv[c] * ( dinv[c]*xs[c,:] + sum_r dinv[r]*xs[r,:] ) ).
// 16 lanes per node (16B/lane = 256B row), 4 nodes per wave, 4-way edge unroll.
__global__ __launch_bounds__(256) void gather_agg_kernel(const int* __restrict__ rowptr,
                                                         const unsigned* __restrict__ cursor,
                                                         const int* __restrict__ adj,
                                                         const __bf16* __restrict__ xs,
                                                         const float* __restrict__ dinv,
                                                         __bf16* __restrict__ ag, int N) {
    const int t = threadIdx.x;
    const int node = blockIdx.x * 16 + (t >> 4);
    if (node >= N) return;
    const int li = t & 15;

    const bf16x8* xs8 = (const bf16x8*)xs;  // 16 chunks per row
    const float dvn = dinv[node];
    bf16x8 sv = xs8[(size_t)node * 16 + li];
    float acc[8];
    #pragma unroll
    for (int q = 0; q < 8; ++q) acc[q] = dvn * (float)sv[q];

    const int s = rowptr[node];
    const int e = (int)cursor[node];        // == rowptr[node] + deg[node]
    int j = s;
    for (; j + 3 < e; j += 4) {
        int r0 = adj[j], r1 = adj[j + 1], r2 = adj[j + 2], r3 = adj[j + 3];
        float w0 = dinv[r0], w1 = dinv[r1], w2 = dinv[r2], w3 = dinv[r3];
        bf16x8 v0 = xs8[(size_t)r0 * 16 + li];
        bf16x8 v1 = xs8[(size_t)r1 * 16 + li];
        bf16x8 v2 = xs8[(size_t)r2 * 16 + li];
        bf16x8 v3 = xs8[(size_t)r3 * 16 + li];
        #pragma unroll
        for (int q = 0; q < 8; ++q)
            acc[q] += (w0 * (float)v0[q] + w1 * (float)v1[q]) +
                      (w2 * (float)v2[q] + w3 * (float)v3[q]);
    }
    for (; j < e; ++j) {
        int r0 = adj[j];
        float w0 = dinv[r0];
        bf16x8 v0 = xs8[(size_t)r0 * 16 + li];
        #pragma unroll
        for (int q = 0; q < 8; ++q) acc[q] += w0 * (float)v0[q];
    }

    bf16x8 o;
    #pragma unroll
    for (int q = 0; q < 8; ++q) o[q] = (__bf16)(acc[q] * dvn);
    ((bf16x8*)ag)[(size_t)node * 16 + li] = o;
}

// bf16 MFMA GEMM: out[m,n] = prelu( sum_k ag[m,k]*W[n,k] + b[n] ), fp32 out.
// 128x128 tile, K=128 entirely in LDS, 4 waves x (2 m-tiles x 8 n-tiles).
__global__ __launch_bounds__(256) void gemm_mfma_kernel(const __bf16* __restrict__ ag,
                                                        const __bf16* __restrict__ Wb,
                                                        const float* __restrict__ bias,
                                                        const float* __restrict__ alpha,
                                                        float* __restrict__ out, int N) {
    __shared__ __bf16 As[128][136];  // +8 pad
    __shared__ __bf16 Bs[128][136];

    const int rb = blockIdx.x * 128;
    const int cb = blockIdx.y * 128;
    const int t  = threadIdx.x;

    #pragma unroll
    for (int i = 0; i < 8; ++i) {
        int c  = i * 256 + t;
        int r  = c >> 4;
        int k8 = (c & 15) * 8;
        bf16x8 v;
        #pragma unroll
        for (int j = 0; j < 8; ++j) v[j] = (__bf16)0.0f;
        if (rb + r < N) v = *(const bf16x8*)(ag + (size_t)(rb + r) * F_IN + k8);
        *(bf16x8*)&As[r][k8] = v;
    }
    #pragma unroll
    for (int i = 0; i < 8; ++i) {
        int c  = i * 256 + t;
        int r  = c >> 4;
        int k8 = (c & 15) * 8;
        bf16x8 v = *(const bf16x8*)(Wb + (size_t)(cb + r) * F_IN + k8);
        *(bf16x8*)&Bs[r][k8] = v;
    }
    __syncthreads();

    const int w    = t >> 6;
    const int lane = t & 63;
    const int lrow = lane & 15;
    const int lk   = (lane >> 4) * 8;

    f32x4 acc[2][8] = {};
    #pragma unroll
    for (int ks = 0; ks < 4; ++ks) {
        const int k0 = ks * 32 + lk;
        bf16x8 a0 = *(const bf16x8*)&As[w * 32 + lrow][k0];
        bf16x8 a1 = *(const bf16x8*)&As[w * 32 + 16 + lrow][k0];
        #pragma unroll
        for (int tn = 0; tn < 8; ++tn) {
            bf16x8 bfr = *(const bf16x8*)&Bs[tn * 16 + lrow][k0];
            acc[0][tn] = __builtin_amdgcn_mfma_f32_16x16x32_bf16(a0, bfr, acc[0][tn], 0, 0, 0);
            acc[1][tn] = __builtin_amdgcn_mfma_f32_16x16x32_bf16(a1, bfr, acc[1][tn], 0, 0, 0);
        }
    }

    // Epilogue: bias + PReLU; C/D layout col=lane&15, row=(lane>>4)*4+reg.
    float bb[8], aa[8];
    #pragma unroll
    for (int tn = 0; tn < 8; ++tn) {
        int n = cb + tn * 16 + lrow;
        bb[tn] = bias[n];
        aa[tn] = alpha[n];
    }
    const int rloc = (lane >> 4) * 4;
    #pragma unroll
    for (int tm = 0; tm < 2; ++tm) {
        #pragma unroll
        for (int r = 0; r < 4; ++r) {
            int m = rb + w * 32 + tm * 16 + rloc + r;
            if (m >= N) continue;
            #pragma unroll
            for (int tn = 0; tn < 8; ++tn) {
                int n = cb + tn * 16 + lrow;
                float v = acc[tm][tn][r] + bb[tn];
                v = v > 0.f ? v : aa[tn] * v;
                out[(size_t)m * H_OUT + n] = v;
            }
        }
    }
}

extern "C" void kernel_launch(void* const* d_in, const int* in_sizes, int n_in,
                              void* d_out, int out_size, void* d_ws, size_t ws_size,
                              hipStream_t stream) {
    const float* x     = (const float*)d_in[0];
    const int*   ei    = (const int*)d_in[1];
    const float* W     = (const float*)d_in[2];
    const float* b     = (const float*)d_in[3];
    const float* alpha = (const float*)d_in[4];
    float*       out   = (float*)d_out;

    const int N = in_sizes[0] / F_IN;
    const int E = in_sizes[1] / 2;
    const int* row = ei;         // source
    const int* col = ei + E;     // target

    // Workspace layout (64B-aligned sections).
    char* wsb = (char*)d_ws;
    size_t off = 0;
    __bf16* xs = (__bf16*)(wsb + off);  off += (size_t)N * F_IN * 2;     off = (off + 63) & ~(size_t)63;
    __bf16* ag = (__bf16*)(wsb + off);  off += (size_t)N * F_IN * 2;     off = (off + 63) & ~(size_t)63;
    __bf16* Wb = (__bf16*)(wsb + off);  off += (size_t)H_OUT * F_IN * 2; off = (off + 63) & ~(size_t)63;
    unsigned* deg    = (unsigned*)(wsb + off);  off += (size_t)(N + 1) * 4;  // deg[N] = global cursor
    unsigned* cursor = (unsigned*)(wsb + off);  off += (size_t)N * 4;
    float*    dinv   = (float*)(wsb + off);     off += (size_t)N * 4;
    int*      rowptr = (int*)(wsb + off);       off += (size_t)N * 4;
    off = (off + 63) & ~(size_t)63;
    int* adj = (int*)(wsb + off);
    unsigned* total = deg + N;

    const int nw8 = H_OUT * F_IN / 8;
    const int nx8 = N * F_IN / 8;
    const int NWB = (nw8 + 255) / 256;
    const int NXB = (nx8 + 255) / 256;
    const int NEB = (E + 255) / 256;

    // 1. zero deg + global cursor (one memset node)
    hipMemsetAsync(deg, 0, (size_t)(N + 1) * 4, stream);
    // 2. cast W, cast x, count deg -- one multi-role launch
    prep_kernel<<<NWB + NXB + NEB, 256, 0, stream>>>(W, Wb, nw8, x, xs, nx8,
                                                     col, deg, E, NWB, NXB);
    // 3. order-free CSR segment assignment + dinv
    assign_kernel<<<(N + 255) / 256, 256, 0, stream>>>(deg, total, rowptr, cursor, dinv, N);
    // 4. fill adjacency
    fill_csr_kernel<<<(E + 255) / 256, 256, 0, stream>>>(row, col, cursor, adj, E);
    // 5. weighted gather-aggregate
    gather_agg_kernel<<<(N + 15) / 16, 256, 0, stream>>>(rowptr, cursor, adj, xs, dinv, ag, N);
    // 6. MFMA GEMM + bias + PReLU
    dim3 ggrid((N + 127) / 128, H_OUT / 128);
    gemm_mfma_kernel<<<ggrid, 256, 0, stream>>>(ag, Wb, b, alpha, out, N);
}

// Round 7
// 217.551 us; speedup vs baseline: 17.8098x; 1.0089x over previous
//
#include <hip/hip_runtime.h>

// GCN encoder: out = prelu( (Dinv A_hat Dinv X) W^T + b ).
// R7: atomic-free CSR fill (position recorded during count phase) +
// 8-wide gather unroll (avg degree = 8). 6 graph nodes.

#define F_IN 128
#define H_OUT 512

typedef __bf16 bf16x8 __attribute__((ext_vector_type(8)));
typedef float  f32x4  __attribute__((ext_vector_type(4)));

// Multi-role prep: blocks [0,NWB) cast W->bf16; [NWB,NWB+NXB) cast x->bf16;
// rest count in-degrees, recording each edge's intra-segment position.
__global__ __launch_bounds__(256) void prep_kernel(const float* __restrict__ W,
                                                   __bf16* __restrict__ Wb, int nw8,
                                                   const float* __restrict__ x,
                                                   __bf16* __restrict__ xs, int nx8,
                                                   const int* __restrict__ col,
                                                   unsigned* __restrict__ deg,
                                                   unsigned* __restrict__ pos, int E,
                                                   int NWB, int NXB) {
    const int b = blockIdx.x, t = threadIdx.x;
    if (b < NWB) {
        int i = b * 256 + t;
        if (i >= nw8) return;
        float4 a0 = ((const float4*)W)[i * 2];
        float4 a1 = ((const float4*)W)[i * 2 + 1];
        bf16x8 v;
        v[0] = (__bf16)a0.x; v[1] = (__bf16)a0.y; v[2] = (__bf16)a0.z; v[3] = (__bf16)a0.w;
        v[4] = (__bf16)a1.x; v[5] = (__bf16)a1.y; v[6] = (__bf16)a1.z; v[7] = (__bf16)a1.w;
        ((bf16x8*)Wb)[i] = v;
    } else if (b < NWB + NXB) {
        int i = (b - NWB) * 256 + t;
        if (i >= nx8) return;
        float4 a0 = ((const float4*)x)[i * 2];
        float4 a1 = ((const float4*)x)[i * 2 + 1];
        bf16x8 v;
        v[0] = (__bf16)a0.x; v[1] = (__bf16)a0.y; v[2] = (__bf16)a0.z; v[3] = (__bf16)a0.w;
        v[4] = (__bf16)a1.x; v[5] = (__bf16)a1.y; v[6] = (__bf16)a1.z; v[7] = (__bf16)a1.w;
        ((bf16x8*)xs)[i] = v;
    } else {
        int e = (b - NWB - NXB) * 256 + t;
        if (e < E) pos[e] = atomicAdd(&deg[col[e]], 1u);  // returns old = position
    }
}

// Order-free CSR segment assignment: wave-scan deg, one atomic per wave.
__global__ __launch_bounds__(256) void assign_kernel(const unsigned* __restrict__ deg,
                                                     unsigned* __restrict__ total,
                                                     int* __restrict__ rowptr,
                                                     float* __restrict__ dinv, int n) {
    const int i = blockIdx.x * 256 + threadIdx.x;
    const int lane = threadIdx.x & 63;
    unsigned d = (i < n) ? deg[i] : 0u;
    unsigned x = d;
    #pragma unroll
    for (int o = 1; o < 64; o <<= 1) {
        unsigned y = __shfl_up(x, (unsigned)o, 64);
        if (lane >= o) x += y;
    }
    unsigned tot = __shfl(x, 63, 64);       // wave total
    unsigned wb = 0;
    if (lane == 63) wb = atomicAdd(total, tot);
    wb = __shfl(wb, 63, 64);                // wave base
    if (i < n) {
        rowptr[i] = (int)(wb + x - d);      // segment start (exclusive within wave)
        dinv[i]   = rsqrtf((float)(d + 1u));  // +1 self-loop
    }
}

// Atomic-free fill: adj[rowptr[col[e]] + pos[e]] = row[e].
__global__ __launch_bounds__(256) void fill_csr_kernel(const int* __restrict__ row,
                                                       const int* __restrict__ col,
                                                       const unsigned* __restrict__ pos,
                                                       const int* __restrict__ rowptr,
                                                       int* __restrict__ adj, int E) {
    int e = blockIdx.x * 256 + threadIdx.x;
    if (e >= E) return;
    adj[rowptr[col[e]] + (int)pos[e]] = row[e];
}

// Aggregate: ag[c,:] = bf16( dinv[c] * ( dinv[c]*xs[c,:] + sum_r dinv[r]*xs[r,:] ) ).
// 16 lanes per node (16B/lane = 256B row), 4 nodes per wave, 8-wide edge unroll
// (avg degree = 8 -> typical node is one unrolled iteration, 8 loads in flight).
__global__ __launch_bounds__(256) void gather_agg_kernel(const int* __restrict__ rowptr,
                                                         const unsigned* __restrict__ deg,
                                                         const int* __restrict__ adj,
                                                         const __bf16* __restrict__ xs,
                                                         const float* __restrict__ dinv,
                                                         __bf16* __restrict__ ag, int N) {
    const int t = threadIdx.x;
    const int node = blockIdx.x * 16 + (t >> 4);
    if (node >= N) return;
    const int li = t & 15;

    const bf16x8* xs8 = (const bf16x8*)xs;  // 16 chunks per row
    const float dvn = dinv[node];
    bf16x8 sv = xs8[(size_t)node * 16 + li];
    float acc[8];
    #pragma unroll
    for (int q = 0; q < 8; ++q) acc[q] = dvn * (float)sv[q];

    const int s = rowptr[node];
    const int e = s + (int)deg[node];
    int j = s;
    for (; j + 7 < e; j += 8) {
        int   r[8]; float wgt[8]; bf16x8 v[8];
        #pragma unroll
        for (int u = 0; u < 8; ++u) r[u] = adj[j + u];
        #pragma unroll
        for (int u = 0; u < 8; ++u) { wgt[u] = dinv[r[u]]; v[u] = xs8[(size_t)r[u] * 16 + li]; }
        #pragma unroll
        for (int u = 0; u < 8; ++u) {
            #pragma unroll
            for (int q = 0; q < 8; ++q) acc[q] += wgt[u] * (float)v[u][q];
        }
    }
    for (; j + 1 < e; j += 2) {
        int r0 = adj[j], r1 = adj[j + 1];
        float w0 = dinv[r0], w1 = dinv[r1];
        bf16x8 v0 = xs8[(size_t)r0 * 16 + li];
        bf16x8 v1 = xs8[(size_t)r1 * 16 + li];
        #pragma unroll
        for (int q = 0; q < 8; ++q) acc[q] += w0 * (float)v0[q] + w1 * (float)v1[q];
    }
    if (j < e) {
        int r0 = adj[j];
        float w0 = dinv[r0];
        bf16x8 v0 = xs8[(size_t)r0 * 16 + li];
        #pragma unroll
        for (int q = 0; q < 8; ++q) acc[q] += w0 * (float)v0[q];
    }

    bf16x8 o;
    #pragma unroll
    for (int q = 0; q < 8; ++q) o[q] = (__bf16)(acc[q] * dvn);
    ((bf16x8*)ag)[(size_t)node * 16 + li] = o;
}

// bf16 MFMA GEMM: out[m,n] = prelu( sum_k ag[m,k]*W[n,k] + b[n] ), fp32 out.
// 128x128 tile, K=128 entirely in LDS, 4 waves x (2 m-tiles x 8 n-tiles).
__global__ __launch_bounds__(256) void gemm_mfma_kernel(const __bf16* __restrict__ ag,
                                                        const __bf16* __restrict__ Wb,
                                                        const float* __restrict__ bias,
                                                        const float* __restrict__ alpha,
                                                        float* __restrict__ out, int N) {
    __shared__ __bf16 As[128][136];  // +8 pad
    __shared__ __bf16 Bs[128][136];

    const int rb = blockIdx.x * 128;
    const int cb = blockIdx.y * 128;
    const int t  = threadIdx.x;

    #pragma unroll
    for (int i = 0; i < 8; ++i) {
        int c  = i * 256 + t;
        int r  = c >> 4;
        int k8 = (c & 15) * 8;
        bf16x8 v;
        #pragma unroll
        for (int j = 0; j < 8; ++j) v[j] = (__bf16)0.0f;
        if (rb + r < N) v = *(const bf16x8*)(ag + (size_t)(rb + r) * F_IN + k8);
        *(bf16x8*)&As[r][k8] = v;
    }
    #pragma unroll
    for (int i = 0; i < 8; ++i) {
        int c  = i * 256 + t;
        int r  = c >> 4;
        int k8 = (c & 15) * 8;
        bf16x8 v = *(const bf16x8*)(Wb + (size_t)(cb + r) * F_IN + k8);
        *(bf16x8*)&Bs[r][k8] = v;
    }
    __syncthreads();

    const int w    = t >> 6;
    const int lane = t & 63;
    const int lrow = lane & 15;
    const int lk   = (lane >> 4) * 8;

    f32x4 acc[2][8] = {};
    #pragma unroll
    for (int ks = 0; ks < 4; ++ks) {
        const int k0 = ks * 32 + lk;
        bf16x8 a0 = *(const bf16x8*)&As[w * 32 + lrow][k0];
        bf16x8 a1 = *(const bf16x8*)&As[w * 32 + 16 + lrow][k0];
        #pragma unroll
        for (int tn = 0; tn < 8; ++tn) {
            bf16x8 bfr = *(const bf16x8*)&Bs[tn * 16 + lrow][k0];
            acc[0][tn] = __builtin_amdgcn_mfma_f32_16x16x32_bf16(a0, bfr, acc[0][tn], 0, 0, 0);
            acc[1][tn] = __builtin_amdgcn_mfma_f32_16x16x32_bf16(a1, bfr, acc[1][tn], 0, 0, 0);
        }
    }

    // Epilogue: bias + PReLU; C/D layout col=lane&15, row=(lane>>4)*4+reg.
    float bb[8], aa[8];
    #pragma unroll
    for (int tn = 0; tn < 8; ++tn) {
        int n = cb + tn * 16 + lrow;
        bb[tn] = bias[n];
        aa[tn] = alpha[n];
    }
    const int rloc = (lane >> 4) * 4;
    #pragma unroll
    for (int tm = 0; tm < 2; ++tm) {
        #pragma unroll
        for (int r = 0; r < 4; ++r) {
            int m = rb + w * 32 + tm * 16 + rloc + r;
            if (m >= N) continue;
            #pragma unroll
            for (int tn = 0; tn < 8; ++tn) {
                int n = cb + tn * 16 + lrow;
                float v = acc[tm][tn][r] + bb[tn];
                v = v > 0.f ? v : aa[tn] * v;
                out[(size_t)m * H_OUT + n] = v;
            }
        }
    }
}

extern "C" void kernel_launch(void* const* d_in, const int* in_sizes, int n_in,
                              void* d_out, int out_size, void* d_ws, size_t ws_size,
                              hipStream_t stream) {
    const float* x     = (const float*)d_in[0];
    const int*   ei    = (const int*)d_in[1];
    const float* W     = (const float*)d_in[2];
    const float* b     = (const float*)d_in[3];
    const float* alpha = (const float*)d_in[4];
    float*       out   = (float*)d_out;

    const int N = in_sizes[0] / F_IN;
    const int E = in_sizes[1] / 2;
    const int* row = ei;         // source
    const int* col = ei + E;     // target

    // Workspace layout (64B-aligned sections).
    char* wsb = (char*)d_ws;
    size_t off = 0;
    __bf16* xs = (__bf16*)(wsb + off);  off += (size_t)N * F_IN * 2;     off = (off + 63) & ~(size_t)63;
    __bf16* ag = (__bf16*)(wsb + off);  off += (size_t)N * F_IN * 2;     off = (off + 63) & ~(size_t)63;
    __bf16* Wb = (__bf16*)(wsb + off);  off += (size_t)H_OUT * F_IN * 2; off = (off + 63) & ~(size_t)63;
    unsigned* deg    = (unsigned*)(wsb + off);  off += (size_t)(N + 1) * 4;  // deg[N] = scan total
    float*    dinv   = (float*)(wsb + off);     off += (size_t)N * 4;
    int*      rowptr = (int*)(wsb + off);       off += (size_t)N * 4;
    off = (off + 63) & ~(size_t)63;
    unsigned* pos = (unsigned*)(wsb + off);     off += (size_t)E * 4;
    off = (off + 63) & ~(size_t)63;
    int* adj = (int*)(wsb + off);
    unsigned* total = deg + N;

    const int nw8 = H_OUT * F_IN / 8;
    const int nx8 = N * F_IN / 8;
    const int NWB = (nw8 + 255) / 256;
    const int NXB = (nx8 + 255) / 256;
    const int NEB = (E + 255) / 256;

    // 1. zero deg + scan total
    hipMemsetAsync(deg, 0, (size_t)(N + 1) * 4, stream);
    // 2. cast W, cast x, count deg + record positions
    prep_kernel<<<NWB + NXB + NEB, 256, 0, stream>>>(W, Wb, nw8, x, xs, nx8,
                                                     col, deg, pos, E, NWB, NXB);
    // 3. segment assignment + dinv
    assign_kernel<<<(N + 255) / 256, 256, 0, stream>>>(deg, total, rowptr, dinv, N);
    // 4. atomic-free fill
    fill_csr_kernel<<<(E + 255) / 256, 256, 0, stream>>>(row, col, pos, rowptr, adj, E);
    // 5. weighted gather-aggregate
    gather_agg_kernel<<<(N + 15) / 16, 256, 0, stream>>>(rowptr, deg, adj, xs, dinv, ag, N);
    // 6. MFMA GEMM + bias + PReLU
    dim3 ggrid((N + 127) / 128, H_OUT / 128);
    gemm_mfma_kernel<<<ggrid, 256, 0, stream>>>(ag, Wb, b, alpha, out, N);
}